// Round 1
// baseline (288.576 us; speedup 1.0000x reference)
//
#include <hip/hip_runtime.h>

// Fused loss: 0.2 * mean(dx^2 - dy^2) + 0.8 * masked-MSE(target>0)
// where dx/dy = sobel_{x,y}(gauss3x3(pred - target)) with reflect-101 padding
// at BOTH conv stages (cv2 semantics, symmetric gaussian => blur of reflected
// input == reflect of blurred output, so one fused halo pass is exact).

#define TW 128           // tile width
#define TH 32            // tile height
#define EW (TW + 4)      // e-tile width  (halo 2)
#define EH (TH + 4)      // e-tile height
#define BW (TW + 2)      // blur-tile width (halo 1)
#define BH (TH + 2)      // blur-tile height

__device__ __forceinline__ int reflect101(int i, int n) {
    // valid for i in [-(n-1), 2n-2]; we only need +/-2
    if (i < 0) i = -i;
    if (i >= n) i = 2 * n - 2 - i;
    return i;
}

__global__ __launch_bounds__(256) void loss_main(
    const float* __restrict__ pred, const float* __restrict__ target,
    double* __restrict__ acc, int H, int W)
{
    __shared__ float esh[EH][EW];   // e = pred - target, halo 2
    __shared__ float bsh[BH][BW];   // gauss3x3(e), halo 1
    __shared__ float partials[4][3];

    const int tid = threadIdx.x;
    const int r0 = blockIdx.y * TH;
    const int c0 = blockIdx.x * TW;

    float mse_local = 0.f;
    float cnt_local = 0.f;

    // ---- Stage 1: load e with reflect-101 halo; fuse masked MSE on in-tile px
    for (int idx = tid; idx < EH * EW; idx += 256) {
        int ly = idx / EW;
        int lx = idx - ly * EW;
        int gr = reflect101(r0 - 2 + ly, H);
        int gc = reflect101(c0 - 2 + lx, W);
        float p = pred[gr * W + gc];
        float t = target[gr * W + gc];
        esh[ly][lx] = p - t;
        // each in-tile (ly,lx) maps to a unique global pixel -> count once
        if (ly >= 2 && ly < 2 + TH && lx >= 2 && lx < 2 + TW) {
            if (t > 0.f) {
                float d = t - p;
                mse_local += d * d;
                cnt_local += 1.f;
            }
        }
    }
    __syncthreads();

    // ---- Stage 2: 3x3 gaussian (0.25,0.5,0.25 outer) into bsh (halo 1)
    for (int idx = tid; idx < BH * BW; idx += 256) {
        int by = idx / BW;
        int bx = idx - by * BW;
        float s =
            0.0625f * (esh[by][bx]     + esh[by][bx+2] +
                       esh[by+2][bx]   + esh[by+2][bx+2]) +
            0.125f  * (esh[by][bx+1]   + esh[by+1][bx] +
                       esh[by+1][bx+2] + esh[by+2][bx+1]) +
            0.25f   *  esh[by+1][bx+1];
        bsh[by][bx] = s;
    }
    __syncthreads();

    // ---- Stage 3: sobel x/y, accumulate dx^2 - dy^2 (faithful sign per ref)
    float g_local = 0.f;
    for (int idx = tid; idx < TH * TW; idx += 256) {
        int y = idx / TW;
        int x = idx - y * TW;
        float tl = bsh[y][x],     tc = bsh[y][x+1],   tr = bsh[y][x+2];
        float ml = bsh[y+1][x],                       mr = bsh[y+1][x+2];
        float bl = bsh[y+2][x],   bc = bsh[y+2][x+1], br = bsh[y+2][x+2];
        float dx = (tr + 2.f*mr + br) - (tl + 2.f*ml + bl);
        float dy = (bl + 2.f*bc + br) - (tl + 2.f*tc + tr);
        g_local += dx*dx - dy*dy;
    }

    // ---- Reduction: wave64 shuffle -> LDS -> double atomics
    for (int off = 32; off > 0; off >>= 1) {
        mse_local += __shfl_down(mse_local, off, 64);
        cnt_local += __shfl_down(cnt_local, off, 64);
        g_local   += __shfl_down(g_local,   off, 64);
    }
    int wave = tid >> 6;
    int lane = tid & 63;
    if (lane == 0) {
        partials[wave][0] = mse_local;
        partials[wave][1] = cnt_local;
        partials[wave][2] = g_local;
    }
    __syncthreads();
    if (tid == 0) {
        float m = 0.f, c = 0.f, g = 0.f;
        for (int w = 0; w < 4; ++w) {
            m += partials[w][0];
            c += partials[w][1];
            g += partials[w][2];
        }
        atomicAdd(&acc[0], (double)m);
        atomicAdd(&acc[1], (double)c);
        atomicAdd(&acc[2], (double)g);
    }
}

__global__ void loss_final(const double* __restrict__ acc,
                           float* __restrict__ out, double inv_hw)
{
    double cnt = acc[1] < 1.0 ? 1.0 : acc[1];
    double mae = acc[0] / cnt;
    double G   = acc[2] * inv_hw;
    out[0] = (float)(0.2 * G + 0.8 * mae);
}

extern "C" void kernel_launch(void* const* d_in, const int* in_sizes, int n_in,
                              void* d_out, int out_size, void* d_ws, size_t ws_size,
                              hipStream_t stream) {
    const float* pred   = (const float*)d_in[0];
    const float* target = (const float*)d_in[1];
    float* out  = (float*)d_out;
    double* acc = (double*)d_ws;

    const int H = 4096, W = 4096;

    hipMemsetAsync(acc, 0, 3 * sizeof(double), stream);

    dim3 grid(W / TW, H / TH);   // 32 x 128 = 4096 blocks
    loss_main<<<grid, 256, 0, stream>>>(pred, target, acc, H, W);
    loss_final<<<1, 1, 0, stream>>>(acc, out, 1.0 / ((double)H * (double)W));
}

// Round 2
// 204.288 us; speedup vs baseline: 1.4126x; 1.4126x over previous
//
#include <hip/hip_runtime.h>

// Fused loss: 0.2 * mean(dx^2 - dy^2) + 0.8 * masked-MSE(target>0)
// Key identity: conv is linear and separable ->
//   dx = corr(e, Sv ⊗ D), dy = corr(e, D ⊗ Sv), e = pred - target
//   Sv = g1*smooth = [0.25, 1, 1.5, 1, 0.25]  (vertical for dx)
//   D  = g1*deriv  = [-0.25, -0.5, 0, 0.5, 0.25]
// reflect-101 pad by 2 on e is exact (gaussian symmetric => blur commutes
// with reflection; verified absmax 0.0 in R1 with the 2-stage version).
//
// Structure: one WAVE owns a 256-col x 16-row strip. 5-row rolling float4
// window in registers, horizontal halo via __shfl, lanes 0/63 load the 2
// out-of-strip halo columns themselves. No LDS staging, no syncthreads in
// the hot loop -> loads stay in flight.

#define RSTRIP 16   // rows per wave strip

__device__ __forceinline__ int reflect101(int i, int n) {
    if (i < 0) i = -i;
    if (i >= n) i = 2 * n - 2 - i;
    return i;
}

__global__ __launch_bounds__(256) void loss_main(
    const float* __restrict__ pred, const float* __restrict__ target,
    double* __restrict__ acc, int H, int W)
{
    __shared__ float partials[4][3];

    const int tid  = threadIdx.x;
    const int lane = tid & 63;
    const int wid  = tid >> 6;
    const int cs   = (blockIdx.x * 4 + wid) * 256;  // wave strip start col
    const int rs   = blockIdx.y * RSTRIP;           // strip start row
    const int c    = cs + lane * 4;                 // this lane's first col

    // halo columns: lane 0 supplies cols cs-2,cs-1; lane 63 cols cs+256,cs+257
    const bool isL = (lane == 0);
    const bool isR = (lane == 63);
    const bool hload = isL || isR;
    int hcol = 0; bool hswap = false;
    if (isL) { hswap = (cs == 0);       hcol = hswap ? 1       : cs - 2;   }
    if (isR) { hswap = (cs + 256 == W); hcol = hswap ? (W - 3) : cs + 256; }

    float mse = 0.f, cnt = 0.f, g = 0.f;

    float4 e0, e1, e2, e3, e4;   // e rows r-2..r+2, this lane's 4 cols
    float2 h0, h1, h2, h3, h4;   // halo-col e (valid on lanes 0/63 only)

    auto loadRow = [&](int lr, float2& he) -> float4 {
        const int r = reflect101(lr, H);
        const float* prow = pred   + (size_t)r * W;
        const float* trow = target + (size_t)r * W;
        const float4 p = *(const float4*)(prow + c);
        const float4 t = *(const float4*)(trow + c);
        float hpx = 0.f, hpy = 0.f, htx = 0.f, hty = 0.f;
        if (hload) {   // 2 lanes only; scalar (hcol may be odd -> no float2)
            hpx = prow[hcol]; hpy = prow[hcol + 1];
            htx = trow[hcol]; hty = trow[hcol + 1];
        }
        const float4 e = make_float4(p.x - t.x, p.y - t.y, p.z - t.z, p.w - t.w);
        // masked MSE: count each logical pixel exactly once (in-strip rows only)
        if (lr >= rs && lr < rs + RSTRIP) {
            if (t.x > 0.f) { mse += e.x * e.x; cnt += 1.f; }
            if (t.y > 0.f) { mse += e.y * e.y; cnt += 1.f; }
            if (t.z > 0.f) { mse += e.z * e.z; cnt += 1.f; }
            if (t.w > 0.f) { mse += e.w * e.w; cnt += 1.f; }
        }
        const float ex = hpx - htx, ey = hpy - hty;
        he = hswap ? make_float2(ey, ex) : make_float2(ex, ey);
        return e;
    };

    auto computeRow = [&]() {
        float4 sv, dv;
        sv.x = 0.25f*(e0.x + e4.x) + (e1.x + e3.x) + 1.5f*e2.x;
        sv.y = 0.25f*(e0.y + e4.y) + (e1.y + e3.y) + 1.5f*e2.y;
        sv.z = 0.25f*(e0.z + e4.z) + (e1.z + e3.z) + 1.5f*e2.z;
        sv.w = 0.25f*(e0.w + e4.w) + (e1.w + e3.w) + 1.5f*e2.w;
        dv.x = 0.25f*(e4.x - e0.x) + 0.5f*(e3.x - e1.x);
        dv.y = 0.25f*(e4.y - e0.y) + 0.5f*(e3.y - e1.y);
        dv.z = 0.25f*(e4.z - e0.z) + 0.5f*(e3.z - e1.z);
        dv.w = 0.25f*(e4.w - e0.w) + 0.5f*(e3.w - e1.w);

        const float svhx = 0.25f*(h0.x + h4.x) + (h1.x + h3.x) + 1.5f*h2.x;
        const float svhy = 0.25f*(h0.y + h4.y) + (h1.y + h3.y) + 1.5f*h2.y;
        const float dvhx = 0.25f*(h4.x - h0.x) + 0.5f*(h3.x - h1.x);
        const float dvhy = 0.25f*(h4.y - h0.y) + 0.5f*(h3.y - h1.y);

        float sv_m2 = __shfl_up(sv.z, 1, 64);
        float sv_m1 = __shfl_up(sv.w, 1, 64);
        float sv_p4 = __shfl_down(sv.x, 1, 64);
        float sv_p5 = __shfl_down(sv.y, 1, 64);
        float dv_m2 = __shfl_up(dv.z, 1, 64);
        float dv_m1 = __shfl_up(dv.w, 1, 64);
        float dv_p4 = __shfl_down(dv.x, 1, 64);
        float dv_p5 = __shfl_down(dv.y, 1, 64);
        if (isL) { sv_m2 = svhx; sv_m1 = svhy; dv_m2 = dvhx; dv_m1 = dvhy; }
        if (isR) { sv_p4 = svhx; sv_p5 = svhy; dv_p4 = dvhx; dv_p5 = dvhy; }

        // dx(x) = 0.25*(sv(x+2)-sv(x-2)) + 0.5*(sv(x+1)-sv(x-1))
        const float dx0 = 0.25f*(sv.z - sv_m2) + 0.5f*(sv.y - sv_m1);
        const float dx1 = 0.25f*(sv.w - sv_m1) + 0.5f*(sv.z - sv.x);
        const float dx2 = 0.25f*(sv_p4 - sv.x) + 0.5f*(sv.w - sv.y);
        const float dx3 = 0.25f*(sv_p5 - sv.y) + 0.5f*(sv_p4 - sv.z);
        // dy(x) = 0.25*(dv(x-2)+dv(x+2)) + (dv(x-1)+dv(x+1)) + 1.5*dv(x)
        const float dy0 = 0.25f*(dv_m2 + dv.z) + (dv_m1 + dv.y) + 1.5f*dv.x;
        const float dy1 = 0.25f*(dv_m1 + dv.w) + (dv.x + dv.z) + 1.5f*dv.y;
        const float dy2 = 0.25f*(dv.x + dv_p4) + (dv.y + dv.w) + 1.5f*dv.z;
        const float dy3 = 0.25f*(dv.y + dv_p5) + (dv.z + dv_p4) + 1.5f*dv.w;

        g += (dx0*dx0 - dy0*dy0) + (dx1*dx1 - dy1*dy1)
           + (dx2*dx2 - dy2*dy2) + (dx3*dx3 - dy3*dy3);
    };

    e0 = loadRow(rs - 2, h0);
    e1 = loadRow(rs - 1, h1);
    e2 = loadRow(rs,     h2);
    e3 = loadRow(rs + 1, h3);
    e4 = loadRow(rs + 2, h4);

#pragma unroll 4
    for (int k = 0; k < RSTRIP - 1; ++k) {
        float2 hn;
        float4 en = loadRow(rs + k + 3, hn);  // prefetch next row, 1 ahead
        computeRow();
        e0 = e1; e1 = e2; e2 = e3; e3 = e4; e4 = en;
        h0 = h1; h1 = h2; h2 = h3; h3 = h4; h4 = hn;
    }
    computeRow();  // last row, nothing left to load

    // ---- reduction: wave shuffle -> LDS partials -> double atomics
    for (int off = 32; off > 0; off >>= 1) {
        mse += __shfl_down(mse, off, 64);
        cnt += __shfl_down(cnt, off, 64);
        g   += __shfl_down(g,   off, 64);
    }
    if (lane == 0) {
        partials[wid][0] = mse;
        partials[wid][1] = cnt;
        partials[wid][2] = g;
    }
    __syncthreads();
    if (tid == 0) {
        float m = 0.f, c2 = 0.f, gg = 0.f;
        for (int w = 0; w < 4; ++w) {
            m  += partials[w][0];
            c2 += partials[w][1];
            gg += partials[w][2];
        }
        atomicAdd(&acc[0], (double)m);
        atomicAdd(&acc[1], (double)c2);
        atomicAdd(&acc[2], (double)gg);
    }
}

__global__ void loss_final(const double* __restrict__ acc,
                           float* __restrict__ out, double inv_hw)
{
    double cnt = acc[1] < 1.0 ? 1.0 : acc[1];
    double mae = acc[0] / cnt;
    double G   = acc[2] * inv_hw;
    out[0] = (float)(0.2 * G + 0.8 * mae);
}

extern "C" void kernel_launch(void* const* d_in, const int* in_sizes, int n_in,
                              void* d_out, int out_size, void* d_ws, size_t ws_size,
                              hipStream_t stream) {
    const float* pred   = (const float*)d_in[0];
    const float* target = (const float*)d_in[1];
    float* out  = (float*)d_out;
    double* acc = (double*)d_ws;

    const int H = 4096, W = 4096;

    hipMemsetAsync(acc, 0, 3 * sizeof(double), stream);

    dim3 grid(W / 1024, H / RSTRIP);   // (4, 256) = 1024 blocks, 4096 waves
    loss_main<<<grid, 256, 0, stream>>>(pred, target, acc, H, W);
    loss_final<<<1, 1, 0, stream>>>(acc, out, 1.0 / ((double)H * (double)W));
}

// Round 3
// 199.092 us; speedup vs baseline: 1.4495x; 1.0261x over previous
//
#include <hip/hip_runtime.h>

// Fused loss: 0.2 * mean(dx^2 - dy^2) + 0.8 * masked-MSE(target>0)
// dx = Sv(vert) ∘ D(horiz) on e = pred - target;  dy = D(vert) ∘ Sv(horiz)
//   Sv = [0.25, 1, 1.5, 1, 0.25], D = [-0.25, -0.5, 0, 0.5, 0.25]
// reflect-101 halo of 2 on e (exact; verified absmax 0.0 in R1/R2).
//
// R3 structure: phase A = batched 18x float4 loads/thread -> LDS e-tile
// (deep MLP, latency-tolerant); one sync; phase B = per-thread register
// rolling window over 8 consecutive rows, conflict-free ds_read_b128.

#define TW 256
#define TH 32
#define LW 264   // LDS row width in words; cols 2..261 valid (halo at 2,3,260,261)
#define LH 36    // TH + 4

__device__ __forceinline__ int reflect101(int i, int n) {
    if (i < 0) i = -i;
    if (i >= n) i = 2 * n - 2 - i;
    return i;
}

__global__ __launch_bounds__(256, 3) void loss_main(
    const float* __restrict__ pred, const float* __restrict__ target,
    double* __restrict__ acc, int H, int W)
{
    __shared__ float esh[LH][LW];
    __shared__ float partials[4][3];

    const int tid = threadIdx.x;
    const int r0 = blockIdx.y * TH;
    const int c0 = blockIdx.x * TW;

    float mse = 0.f, cnt = 0.f;

    // ---- halo columns: 144 threads x 1 elem (rows 0..35, 4 halo cols) ----
    float eh = 0.f; int hrow = 0, hlc = 0;
    if (tid < 144) {
        hrow = tid >> 2;
        const int hc = tid & 3;
        hlc = (hc < 2) ? (2 + hc) : (258 + hc);          // LDS col 2,3,260,261
        const int gc = reflect101((hc < 2) ? (c0 - 2 + hc)
                                           : (c0 + 254 + hc), W);
        const int gr = reflect101(r0 - 2 + hrow, H);
        const size_t off = (size_t)gr * W + gc;
        eh = pred[off] - target[off];
    }

    // ---- interior: 36 rows x 64 float4-groups = 9 batched pairs/thread ----
    float4 pv[9], tv[9];
#pragma unroll
    for (int it = 0; it < 9; ++it) {
        const int idx = it * 256 + tid;
        const int row = idx >> 6;
        const int cg  = idx & 63;
        const int gr  = reflect101(r0 - 2 + row, H);
        const size_t off = (size_t)gr * W + c0 + cg * 4;
        pv[it] = *(const float4*)(pred + off);
        tv[it] = *(const float4*)(target + off);
    }

    if (tid < 144) esh[hrow][hlc] = eh;

#pragma unroll
    for (int it = 0; it < 9; ++it) {
        const int idx = it * 256 + tid;
        const int row = idx >> 6;
        const int cg  = idx & 63;
        const float4 p = pv[it], t = tv[it];
        const float4 e = make_float4(p.x - t.x, p.y - t.y,
                                     p.z - t.z, p.w - t.w);
        if (row >= 2 && row < 34) {    // interior rows: this block owns them
            if (t.x > 0.f) { mse += e.x * e.x; cnt += 1.f; }
            if (t.y > 0.f) { mse += e.y * e.y; cnt += 1.f; }
            if (t.z > 0.f) { mse += e.z * e.z; cnt += 1.f; }
            if (t.w > 0.f) { mse += e.w * e.w; cnt += 1.f; }
        }
        *(float4*)&esh[row][4 + cg * 4] = e;   // 16B-aligned, conflict-free
    }
    __syncthreads();

    // ---- phase B: separable conv, rolling 5-row window in registers ----
    // wave w handles LDS output rows 2+8w .. 2+8w+7, lane = col group
    const int cg = tid & 63;              // output cols (LDS) 4+4cg .. 7+4cg
    const int rb = (tid >> 6) * 8;        // window rows rb .. rb+11

    float4 Dh0, Dh1, Dh2, Dh3, Dh4;       // D-horizontal per window row
    float4 Sh0, Sh1, Sh2, Sh3, Sh4;       // Sv-horizontal per window row
    float g = 0.f;

    auto hpass = [&](int rw, float4& D_, float4& S_) {
        const float4 f0 = *(const float4*)&esh[rw][4 * cg];
        const float4 f1 = *(const float4*)&esh[rw][4 * cg + 4];
        const float4 f2 = *(const float4*)&esh[rw][4 * cg + 8];
        D_.x = 0.25f * (f1.z - f0.z) + 0.5f * (f1.y - f0.w);
        D_.y = 0.25f * (f1.w - f0.w) + 0.5f * (f1.z - f1.x);
        D_.z = 0.25f * (f2.x - f1.x) + 0.5f * (f1.w - f1.y);
        D_.w = 0.25f * (f2.y - f1.y) + 0.5f * (f2.x - f1.z);
        S_.x = 0.25f * (f0.z + f1.z) + (f0.w + f1.y) + 1.5f * f1.x;
        S_.y = 0.25f * (f0.w + f1.w) + (f1.x + f1.z) + 1.5f * f1.y;
        S_.z = 0.25f * (f1.x + f2.x) + (f1.y + f1.w) + 1.5f * f1.z;
        S_.w = 0.25f * (f1.y + f2.y) + (f1.z + f2.x) + 1.5f * f1.w;
    };

    hpass(rb + 0, Dh0, Sh0);
    hpass(rb + 1, Dh1, Sh1);
    hpass(rb + 2, Dh2, Sh2);
    hpass(rb + 3, Dh3, Sh3);

#pragma unroll
    for (int k = 0; k < 8; ++k) {
        hpass(rb + 4 + k, Dh4, Sh4);
        // dx = Sv vertical over Dh; dy = D vertical over Sh
        const float dx0 = 0.25f * (Dh0.x + Dh4.x) + (Dh1.x + Dh3.x) + 1.5f * Dh2.x;
        const float dx1 = 0.25f * (Dh0.y + Dh4.y) + (Dh1.y + Dh3.y) + 1.5f * Dh2.y;
        const float dx2 = 0.25f * (Dh0.z + Dh4.z) + (Dh1.z + Dh3.z) + 1.5f * Dh2.z;
        const float dx3 = 0.25f * (Dh0.w + Dh4.w) + (Dh1.w + Dh3.w) + 1.5f * Dh2.w;
        const float dy0 = 0.25f * (Sh4.x - Sh0.x) + 0.5f * (Sh3.x - Sh1.x);
        const float dy1 = 0.25f * (Sh4.y - Sh0.y) + 0.5f * (Sh3.y - Sh1.y);
        const float dy2 = 0.25f * (Sh4.z - Sh0.z) + 0.5f * (Sh3.z - Sh1.z);
        const float dy3 = 0.25f * (Sh4.w - Sh0.w) + 0.5f * (Sh3.w - Sh1.w);
        g += (dx0 * dx0 - dy0 * dy0) + (dx1 * dx1 - dy1 * dy1)
           + (dx2 * dx2 - dy2 * dy2) + (dx3 * dx3 - dy3 * dy3);
        Dh0 = Dh1; Dh1 = Dh2; Dh2 = Dh3; Dh3 = Dh4;
        Sh0 = Sh1; Sh1 = Sh2; Sh2 = Sh3; Sh3 = Sh4;
    }

    // ---- reduction: wave shuffle -> LDS partials -> double atomics ----
    for (int off = 32; off > 0; off >>= 1) {
        mse += __shfl_down(mse, off, 64);
        cnt += __shfl_down(cnt, off, 64);
        g   += __shfl_down(g,   off, 64);
    }
    const int wid = tid >> 6;
    if ((tid & 63) == 0) {
        partials[wid][0] = mse;
        partials[wid][1] = cnt;
        partials[wid][2] = g;
    }
    __syncthreads();
    if (tid == 0) {
        float m = 0.f, c2 = 0.f, gg = 0.f;
        for (int w = 0; w < 4; ++w) {
            m  += partials[w][0];
            c2 += partials[w][1];
            gg += partials[w][2];
        }
        atomicAdd(&acc[0], (double)m);
        atomicAdd(&acc[1], (double)c2);
        atomicAdd(&acc[2], (double)gg);
    }
}

__global__ void loss_final(const double* __restrict__ acc,
                           float* __restrict__ out, double inv_hw)
{
    double cnt = acc[1] < 1.0 ? 1.0 : acc[1];
    double mae = acc[0] / cnt;
    double G   = acc[2] * inv_hw;
    out[0] = (float)(0.2 * G + 0.8 * mae);
}

extern "C" void kernel_launch(void* const* d_in, const int* in_sizes, int n_in,
                              void* d_out, int out_size, void* d_ws, size_t ws_size,
                              hipStream_t stream) {
    const float* pred   = (const float*)d_in[0];
    const float* target = (const float*)d_in[1];
    float* out  = (float*)d_out;
    double* acc = (double*)d_ws;

    const int H = 4096, W = 4096;

    hipMemsetAsync(acc, 0, 3 * sizeof(double), stream);

    dim3 grid(W / TW, H / TH);   // (16, 128) = 2048 blocks
    loss_main<<<grid, 256, 0, stream>>>(pred, target, acc, H, W);
    loss_final<<<1, 1, 0, stream>>>(acc, out, 1.0 / ((double)H * (double)W));
}

// Round 4
// 196.596 us; speedup vs baseline: 1.4679x; 1.0127x over previous
//
#include <hip/hip_runtime.h>

// Fused loss: 0.2 * mean(dx^2 - dy^2) + 0.8 * masked-MSE(target>0)
// dx = Sv(vert) ∘ D(horiz) on e = pred - target;  dy = D(vert) ∘ Sv(horiz)
//   Sv = [0.25, 1, 1.5, 1, 0.25], D = [-0.25, -0.5, 0, 0.5, 0.25]
// reflect-101 halo of 2 on e (exact; absmax 0.0 in R1/R2/R3).
//
// R4: phase A stages raw p and t tiles via __builtin_amdgcn_global_load_lds
// width=16 (async DMA, no VGPR round-trip -> 18 row-loads in flight per wave;
// R3's register batch was defeated by the allocator, VGPR_Count=52 proved it).
// One row segment (256 floats = 64 lanes x 16B) = one async instruction.
// Halo cols via 144 scalar loads. Phase B: rolling-window separable conv
// reading p,t from LDS (subtract inline), conflict-free b128, MSE fused
// disjointly per wave.

#define TW 256
#define TH 32
#define LROWS 36   // TH + 4
#define LW 264     // row stride (words): interior cols 4..259, halo 2,3,260,261
                   // stride 1056B (16B-multiple, required for async dst align)

__device__ __forceinline__ int reflect101(int i, int n) {
    if (i < 0) i = -i;
    if (i >= n) i = 2 * n - 2 - i;
    return i;
}

__device__ __forceinline__ void async16(const float* g, float* l) {
    __builtin_amdgcn_global_load_lds(
        (const __attribute__((address_space(1))) void*)g,
        (__attribute__((address_space(3))) void*)l,
        16, 0, 0);
}

__global__ __launch_bounds__(256) void loss_main(
    const float* __restrict__ pred, const float* __restrict__ target,
    double* __restrict__ acc, int H, int W)
{
    __shared__ float psh[LROWS][LW];
    __shared__ float tsh[LROWS][LW];
    __shared__ float partials[4][3];

    const int tid  = threadIdx.x;
    const int lane = tid & 63;
    const int w    = tid >> 6;
    const int r0 = blockIdx.y * TH;
    const int c0 = blockIdx.x * TW;

    // ---- phase A: async global->LDS, 18 row-segments per wave, all in flight
    // j<9: pred rows (idx 0..35), j>=9: target rows (idx-36). Wave-uniform.
#pragma unroll
    for (int j = 0; j < 18; ++j) {
        const int idx = j * 4 + w;
        const int row = (j >= 9) ? idx - 36 : idx;
        const int gr  = reflect101(r0 - 2 + row, H);
        const size_t goff = (size_t)gr * W + c0 + lane * 4;
        if (j >= 9) async16(target + goff, &tsh[row][4]);
        else        async16(pred   + goff, &psh[row][4]);
    }

    // ---- halo columns: 144 threads, 1 (row, halo-col) pair each, both tensors
    if (tid < 144) {
        const int row = tid >> 2;
        const int hc  = tid & 3;
        const int lc  = (hc < 2) ? (2 + hc) : (258 + hc);   // 2,3,260,261
        const int gc  = reflect101((hc < 2) ? (c0 - 2 + hc)
                                            : (c0 + 254 + hc), W);
        const int gr  = reflect101(r0 - 2 + row, H);
        const size_t off = (size_t)gr * W + gc;
        psh[row][lc] = pred[off];
        tsh[row][lc] = target[off];
    }
    __syncthreads();   // drains vmcnt(0): async DMA + halo ds_writes complete

    // ---- phase B: separable conv + masked MSE, rolling 5-row window ----
    const int cg = lane;            // output LDS cols 4+4cg .. 7+4cg
    const int rb = w * 8;           // window rows rb .. rb+11
    float mse = 0.f, cnt = 0.f, g = 0.f;

    float4 D0, D1, D2, D3, D4, S0, S1, S2, S3, S4;

    // horizontal pass on row rw; e = p - t computed inline.
    // doMse: accumulate masked MSE for this row's 4 interior pixels
    // (rows rb+2..rb+9 per wave -> disjoint union = LDS rows 2..33).
    auto hpass = [&](int rw, bool doMse, float4& D_, float4& S_) {
        const float4 p0 = *(const float4*)&psh[rw][4 * cg];
        const float4 p1 = *(const float4*)&psh[rw][4 * cg + 4];
        const float4 p2 = *(const float4*)&psh[rw][4 * cg + 8];
        const float4 t0 = *(const float4*)&tsh[rw][4 * cg];
        const float4 t1 = *(const float4*)&tsh[rw][4 * cg + 4];
        const float4 t2 = *(const float4*)&tsh[rw][4 * cg + 8];
        const float e0z = p0.z - t0.z, e0w = p0.w - t0.w;
        const float e1x = p1.x - t1.x, e1y = p1.y - t1.y;
        const float e1z = p1.z - t1.z, e1w = p1.w - t1.w;
        const float e2x = p2.x - t2.x, e2y = p2.y - t2.y;
        D_.x = 0.25f * (e1z - e0z) + 0.5f * (e1y - e0w);
        D_.y = 0.25f * (e1w - e0w) + 0.5f * (e1z - e1x);
        D_.z = 0.25f * (e2x - e1x) + 0.5f * (e1w - e1y);
        D_.w = 0.25f * (e2y - e1y) + 0.5f * (e2x - e1z);
        S_.x = 0.25f * (e0z + e1z) + (e0w + e1y) + 1.5f * e1x;
        S_.y = 0.25f * (e0w + e1w) + (e1x + e1z) + 1.5f * e1y;
        S_.z = 0.25f * (e1x + e2x) + (e1y + e1w) + 1.5f * e1z;
        S_.w = 0.25f * (e1y + e2y) + (e1z + e2x) + 1.5f * e1w;
        if (doMse) {
            if (t1.x > 0.f) { mse += e1x * e1x; cnt += 1.f; }
            if (t1.y > 0.f) { mse += e1y * e1y; cnt += 1.f; }
            if (t1.z > 0.f) { mse += e1z * e1z; cnt += 1.f; }
            if (t1.w > 0.f) { mse += e1w * e1w; cnt += 1.f; }
        }
    };

    hpass(rb + 0, false, D0, S0);
    hpass(rb + 1, false, D1, S1);
    hpass(rb + 2, true,  D2, S2);
    hpass(rb + 3, true,  D3, S3);

#pragma unroll
    for (int k = 0; k < 8; ++k) {
        hpass(rb + 4 + k, (k < 6), D4, S4);
        const float dx0 = 0.25f * (D0.x + D4.x) + (D1.x + D3.x) + 1.5f * D2.x;
        const float dx1 = 0.25f * (D0.y + D4.y) + (D1.y + D3.y) + 1.5f * D2.y;
        const float dx2 = 0.25f * (D0.z + D4.z) + (D1.z + D3.z) + 1.5f * D2.z;
        const float dx3 = 0.25f * (D0.w + D4.w) + (D1.w + D3.w) + 1.5f * D2.w;
        const float dy0 = 0.25f * (S4.x - S0.x) + 0.5f * (S3.x - S1.x);
        const float dy1 = 0.25f * (S4.y - S0.y) + 0.5f * (S3.y - S1.y);
        const float dy2 = 0.25f * (S4.z - S0.z) + 0.5f * (S3.z - S1.z);
        const float dy3 = 0.25f * (S4.w - S0.w) + 0.5f * (S3.w - S1.w);
        g += (dx0 * dx0 - dy0 * dy0) + (dx1 * dx1 - dy1 * dy1)
           + (dx2 * dx2 - dy2 * dy2) + (dx3 * dx3 - dy3 * dy3);
        D0 = D1; D1 = D2; D2 = D3; D3 = D4;
        S0 = S1; S1 = S2; S2 = S3; S3 = S4;
    }

    // ---- reduction: wave shuffle -> LDS partials -> double atomics ----
    for (int off = 32; off > 0; off >>= 1) {
        mse += __shfl_down(mse, off, 64);
        cnt += __shfl_down(cnt, off, 64);
        g   += __shfl_down(g,   off, 64);
    }
    if (lane == 0) {
        partials[w][0] = mse;
        partials[w][1] = cnt;
        partials[w][2] = g;
    }
    __syncthreads();
    if (tid == 0) {
        float m = 0.f, c2 = 0.f, gg = 0.f;
        for (int wv = 0; wv < 4; ++wv) {
            m  += partials[wv][0];
            c2 += partials[wv][1];
            gg += partials[wv][2];
        }
        atomicAdd(&acc[0], (double)m);
        atomicAdd(&acc[1], (double)c2);
        atomicAdd(&acc[2], (double)gg);
    }
}

__global__ void loss_final(const double* __restrict__ acc,
                           float* __restrict__ out, double inv_hw)
{
    double cnt = acc[1] < 1.0 ? 1.0 : acc[1];
    double mae = acc[0] / cnt;
    double G   = acc[2] * inv_hw;
    out[0] = (float)(0.2 * G + 0.8 * mae);
}

extern "C" void kernel_launch(void* const* d_in, const int* in_sizes, int n_in,
                              void* d_out, int out_size, void* d_ws, size_t ws_size,
                              hipStream_t stream) {
    const float* pred   = (const float*)d_in[0];
    const float* target = (const float*)d_in[1];
    float* out  = (float*)d_out;
    double* acc = (double*)d_ws;

    const int H = 4096, W = 4096;

    hipMemsetAsync(acc, 0, 3 * sizeof(double), stream);

    dim3 grid(W / TW, H / TH);   // (16, 128) = 2048 blocks
    loss_main<<<grid, 256, 0, stream>>>(pred, target, acc, H, W);
    loss_final<<<1, 1, 0, stream>>>(acc, out, 1.0 / ((double)H * (double)W));
}